// Round 14
// baseline (3185.945 us; speedup 1.0000x reference)
//
#include <hip/hip_runtime.h>
#include <hip/hip_bf16.h>
#include <math.h>

// LSTM (N=64, T=1024, D=H=512), persistent bf16-MFMA v7: self-tagged h cells.
//
// ws layout:
//   Wt   bf16 [2048][1024] @ 0   (4 MB)   [Wx;Wh]^T, col-major-K
//   hb32 u32  [2][64][512] @ 4MB (256 KB) tagged h: (tag<<16)|bf16, parity-buffered
//
// 256 blocks = 4 row-groups (16 rows) x 64 j-groups (8 h-cols x 4 gates).
// 512 thr = 8 waves = 2 col-tiles (ct) x 4 K-quarters (kq).
// Exchange protocol (the v7 change): producers store tagged u32 h cells
// (sc0sc1) and DO NOT drain/flag; consumers bulk-load the tagged panel
// (coalesced, disjoint 64B/thread), retry only failing lanes, strip tags,
// stage into the v6 swizzled LDS panel. One L3 RT on the critical path.
// Safety: parity ping-pong + transitive argument (see r10 comments);
// init rewrites both parities each launch (tag0 | sentinel).

#define TT 1024
#define HH 512
#define FH 2048
#define KK 1024
#define NN 64

typedef __attribute__((ext_vector_type(8))) short bf16x8;
typedef __attribute__((ext_vector_type(4))) float f32x4;
typedef __attribute__((ext_vector_type(4))) int int4v;
typedef __attribute__((ext_vector_type(2))) unsigned int uint2v;

__device__ __forceinline__ unsigned short f2bf(float f) {
    return __builtin_bit_cast(unsigned short, __float2bfloat16(f));
}

// ---------------- prep: Wt[col][k] = [Wx;Wh]^T bf16 ----------------
__global__ __launch_bounds__(256)
void prep_wt(const float* __restrict__ Wx, const float* __restrict__ Wh,
             unsigned short* __restrict__ Wt)
{
    __shared__ float tile[64][65];
    const int c0  = blockIdx.x * 64;
    const int k0  = blockIdx.y * 64;
    const int tid = threadIdx.x;

    #pragma unroll
    for (int it = 0; it < 16; ++it) {
        int idx = it * 256 + tid;
        int kk = idx >> 6, cc = idx & 63;
        int k = k0 + kk;
        float w = (k < 512) ? Wx[(size_t)k * FH + c0 + cc]
                            : Wh[(size_t)(k - 512) * FH + c0 + cc];
        tile[kk][cc] = w;
    }
    __syncthreads();

    #pragma unroll
    for (int it = 0; it < 8; ++it) {
        int idx = it * 256 + tid;
        int cc = idx >> 5, kp = idx & 31;
        unsigned int lo = f2bf(tile[kp * 2][cc]);
        unsigned int hi = f2bf(tile[kp * 2 + 1][cc]);
        *(unsigned int*)(Wt + (size_t)(c0 + cc) * KK + k0 + kp * 2) =
            lo | (hi << 16);
    }
}

// ---------------- init: parity0 = (tag0|h0), parity1 = sentinel ----------------
__global__ __launch_bounds__(256)
void lstm_init(const float* __restrict__ h0, unsigned int* __restrict__ hb32)
{
    int id = blockIdx.x * 256 + threadIdx.x;
    if (id < NN * HH) {
        unsigned int v0 = (unsigned int)f2bf(h0[id]);   // tag 0 | h0
        unsigned int v1 = 0xFFFF0000u;                  // sentinel tag
        unsigned int* p0 = hb32 + id;
        unsigned int* p1 = hb32 + NN * HH + id;
        asm volatile("global_store_dword %0, %1, off sc0 sc1" :: "v"(p0), "v"(v0) : "memory");
        asm volatile("global_store_dword %0, %1, off sc0 sc1" :: "v"(p1), "v"(v1) : "memory");
    }
}

// ---------------- persistent recurrence ----------------
__global__ __launch_bounds__(512)
void lstm_persist(const float* __restrict__ x,
                  const unsigned short* __restrict__ Wt,
                  const float* __restrict__ bias,
                  float* __restrict__ out,
                  unsigned int* __restrict__ hb32)
{
    __shared__ __align__(16) unsigned short Aph[16 * 512];  // 16 KB h panel
    __shared__ float part[8][16][17];                        // 8.7 KB partials

    const int tid  = threadIdx.x;
    const int wv   = tid >> 6;
    const int lane = tid & 63;
    const int l15  = lane & 15;
    const int kh   = lane >> 4;            // 0..3

    const int rg = blockIdx.x >> 6;        // row-group 0..3
    const int jg = blockIdx.x & 63;        // j-group 0..63
    const int j0 = jg * 8;
    const int rowbase = rg * 16;

    const int ct = wv & 1;                 // col-tile 0..1
    const int kq = wv >> 1;                // K-quarter 0..3

    const int lc   = ct * 16 + l15;        // local A-col 0..31
    const int gate = lc >> 3;
    const int jj   = lc & 7;
    const int gcol = gate * HH + j0 + jj;

    // ---- hoist B fragments (32 VGPR) ----
    const unsigned short* wtp = Wt + (size_t)gcol * KK + kh * 8;
    bf16x8 bx[4], bh[4];
    #pragma unroll
    for (int ks = 0; ks < 4; ++ks) {
        bx[ks] = *(const bf16x8*)(wtp + kq * 128 + ks * 32);
        bh[ks] = *(const bf16x8*)(wtp + 512 + kq * 128 + ks * 32);
    }

    // x addressing (reg-direct, MFMA layout)
    const float* xlane = x + (size_t)(rowbase + l15) * TT * 512 + kq * 128 + kh * 8;

    // h-panel read addressing (v6 swizzle)
    const int arow = l15;
    const int rsw  = ((arow & 15) << 3) | ((arow & 3) << 7);

    // tagged-load coords: thread (srow = tid>>5, scol = tid&31);
    // instruction i loads u32 cols [i*128 + scol*4, +4)  (coalesced per instr)
    const int srow  = tid >> 5;
    const int scol  = tid & 31;
    const int rsw_s = ((srow & 15) << 3) | ((srow & 3) << 7);
    const unsigned int* hrow32 = hb32 + (size_t)(rowbase + srow) * HH + scol * 4;

    // gate-phase ownership (tid < 128, waves 0-1)
    const int grow_l = (tid >> 3) & 15;
    const int q      = tid & 7;
    const int grow   = rowbase + grow_l;
    const int gj     = j0 + q;
    float bi = 0.f, bf_ = 0.f, bo = 0.f, bg = 0.f;
    if (tid < 128) {
        bi  = bias[gj];
        bf_ = bias[HH + gj];
        bo  = bias[2 * HH + gj];
        bg  = bias[3 * HH + gj];
    }
    float c_reg = 0.f;
    float* outp = out + (size_t)grow * TT * HH + gj;
    unsigned int* hdst32 = hb32 + (size_t)grow * HH + gj;

    // ---- prologue: x fragments for t=0 ----
    int4v xw[8];
    {
        #pragma unroll
        for (int ks = 0; ks < 4; ++ks) {
            asm volatile("global_load_dwordx4 %0, %1, off" : "=v"(xw[2 * ks])     : "v"(xlane + ks * 32));
            asm volatile("global_load_dwordx4 %0, %1, off" : "=v"(xw[2 * ks + 1]) : "v"(xlane + ks * 32 + 4));
        }
        asm volatile("s_waitcnt vmcnt(0)" ::: "memory");
        __builtin_amdgcn_sched_barrier(0);
    }
    bf16x8 xf[4];
    #pragma unroll
    for (int ks = 0; ks < 4; ++ks) {
        float4 u = __builtin_bit_cast(float4, xw[2 * ks]);
        float4 v = __builtin_bit_cast(float4, xw[2 * ks + 1]);
        bf16x8 a;
        a[0] = (short)f2bf(u.x); a[1] = (short)f2bf(u.y);
        a[2] = (short)f2bf(u.z); a[3] = (short)f2bf(u.w);
        a[4] = (short)f2bf(v.x); a[5] = (short)f2bf(v.y);
        a[6] = (short)f2bf(v.z); a[7] = (short)f2bf(v.w);
        xf[ks] = a;
    }

    for (int t = 0; t < TT; ++t) {
        const int pb = t & 1;
        const unsigned int tg = (unsigned int)t;
        const unsigned int* hp = hrow32 + (size_t)pb * NN * HH;

        // ---- issue tagged h loads (4 coalesced dwordx4 / thread) ----
        int4v hw[4];
        #pragma unroll
        for (int i = 0; i < 4; ++i) {
            asm volatile("global_load_dwordx4 %0, %1, off sc0 sc1"
                         : "=v"(hw[i]) : "v"(hp + i * 128));
        }

        // ---- x-GEMM: 4 MFMA from registers (overlaps the h-load flight) ----
        f32x4 accx = {0.f, 0.f, 0.f, 0.f};
        #pragma unroll
        for (int ks = 0; ks < 4; ++ks)
            accx = __builtin_amdgcn_mfma_f32_16x16x32_bf16(xf[ks], bx[ks], accx, 0, 0, 0);

        // ---- wait + tag-check + exec-masked retry ----
        asm volatile("s_waitcnt vmcnt(0)" ::: "memory");
        __builtin_amdgcn_sched_barrier(0);
        while (true) {
            int ok = 1;
            #pragma unroll
            for (int i = 0; i < 4; ++i) {
                #pragma unroll
                for (int e = 0; e < 4; ++e)
                    ok &= (int)((((unsigned int)hw[i][e]) >> 16) == tg);
            }
            if (__all(ok)) break;
            if (!ok) {
                #pragma unroll
                for (int i = 0; i < 4; ++i) {
                    asm volatile("global_load_dwordx4 %0, %1, off sc0 sc1"
                                 : "=v"(hw[i]) : "v"(hp + i * 128));
                }
            }
            asm volatile("s_waitcnt vmcnt(0)" ::: "memory");
            __builtin_amdgcn_sched_barrier(0);
        }

        // ---- strip tags, stage into swizzled LDS (4 x ds_write_b64) ----
        #pragma unroll
        for (int i = 0; i < 4; ++i) {
            unsigned int lo = ((unsigned int)hw[i][0] & 0xFFFFu) | ((unsigned int)hw[i][1] << 16);
            unsigned int hi = ((unsigned int)hw[i][2] & 0xFFFFu) | ((unsigned int)hw[i][3] << 16);
            int s = (i * 128 + scol * 4) ^ rsw_s;
            uint2v pk = {lo, hi};
            *(uint2v*)(Aph + srow * 512 + s) = pk;
        }
        __syncthreads();   // B3: h panel visible

        // ---- h-GEMM: 4 MFMA from LDS ----
        f32x4 acch = {0.f, 0.f, 0.f, 0.f};
        #pragma unroll
        for (int ks = 0; ks < 4; ++ks) {
            bf16x8 hf = *(const bf16x8*)(Aph + arow * 512
                           + ((kq * 128 + ks * 32 + kh * 8) ^ rsw));
            acch = __builtin_amdgcn_mfma_f32_16x16x32_bf16(hf, bh[ks], acch, 0, 0, 0);
        }
        #pragma unroll
        for (int rr = 0; rr < 4; ++rr)
            part[wv][kh * 4 + rr][l15] = accx[rr] + acch[rr];
        __syncthreads();   // B4: partials ready

        // ---- gates (waves 0-1): reduce, update state, tagged store, NO drain ----
        if (tid < 128) {
            float Ai = bi, Af = bf_, Ao = bo, Ag = bg;
            #pragma unroll
            for (int k2 = 0; k2 < 4; ++k2) {
                Ai += part[2 * k2][grow_l][q];
                Af += part[2 * k2][grow_l][8 + q];
                Ao += part[2 * k2 + 1][grow_l][q];
                Ag += part[2 * k2 + 1][grow_l][8 + q];
            }
            float ig = 1.f / (1.f + __expf(-Ai));
            float fg = 1.f / (1.f + __expf(-Af));
            float og = 1.f / (1.f + __expf(-Ao));
            float eg = __expf(2.f * Ag);
            float gg = 1.f - 2.f / (eg + 1.f);          // tanh(Ag)
            c_reg = fg * c_reg + ig * gg;
            float ec = __expf(2.f * c_reg);
            float tc = 1.f - 2.f / (ec + 1.f);          // tanh(c)
            float hn = og * tc;

            unsigned int hv = (((unsigned int)(t + 1)) << 16) | (unsigned int)f2bf(hn);
            unsigned int* hdst = hdst32 + (size_t)((t + 1) & 1) * NN * HH;
            asm volatile("global_store_dword %0, %1, off sc0 sc1"
                         :: "v"(hdst), "v"(hv) : "memory");
            outp[(size_t)t * HH] = hn;
        }

        // ---- x prefetch + convert for t+1 ----
        if (t + 1 < TT) {
            const float* xp = xlane + (size_t)(t + 1) * 512;
            #pragma unroll
            for (int ks = 0; ks < 4; ++ks) {
                asm volatile("global_load_dwordx4 %0, %1, off" : "=v"(xw[2 * ks])     : "v"(xp + ks * 32));
                asm volatile("global_load_dwordx4 %0, %1, off" : "=v"(xw[2 * ks + 1]) : "v"(xp + ks * 32 + 4));
            }
            asm volatile("s_waitcnt vmcnt(0)" ::: "memory");
            __builtin_amdgcn_sched_barrier(0);
            #pragma unroll
            for (int ks = 0; ks < 4; ++ks) {
                float4 u = __builtin_bit_cast(float4, xw[2 * ks]);
                float4 v = __builtin_bit_cast(float4, xw[2 * ks + 1]);
                bf16x8 a;
                a[0] = (short)f2bf(u.x); a[1] = (short)f2bf(u.y);
                a[2] = (short)f2bf(u.z); a[3] = (short)f2bf(u.w);
                a[4] = (short)f2bf(v.x); a[5] = (short)f2bf(v.y);
                a[6] = (short)f2bf(v.z); a[7] = (short)f2bf(v.w);
                xf[ks] = a;
            }
        }
    }
}

extern "C" void kernel_launch(void* const* d_in, const int* in_sizes, int n_in,
                              void* d_out, int out_size, void* d_ws, size_t ws_size,
                              hipStream_t stream)
{
    const float* x  = (const float*)d_in[0];
    const float* h0 = (const float*)d_in[1];
    const float* Wx = (const float*)d_in[2];
    const float* Wh = (const float*)d_in[3];
    const float* b  = (const float*)d_in[4];
    float* out = (float*)d_out;

    char* ws = (char*)d_ws;
    unsigned short* Wt   = (unsigned short*)ws;                             // 4 MB
    unsigned int*   hb32 = (unsigned int*)(ws + (size_t)4 * 1024 * 1024);   // 256 KB

    prep_wt<<<dim3(32, 16), 256, 0, stream>>>(Wx, Wh, Wt);
    lstm_init<<<128, 256, 0, stream>>>(h0, hb32);
    lstm_persist<<<256, 512, 0, stream>>>(x, Wt, b, out, hb32);
}